// Round 5
// baseline (296.646 us; speedup 1.0000x reference)
//
#include <hip/hip_runtime.h>

typedef __bf16 bf16_t;
typedef __bf16 bf16x8 __attribute__((ext_vector_type(8)));
typedef __bf16 bf16x4 __attribute__((ext_vector_type(4)));
typedef float f32x4 __attribute__((ext_vector_type(4)));
typedef unsigned int u32;

#define AS1 __attribute__((address_space(1)))
#define AS3 __attribute__((address_space(3)))

#define ASTR 72   // attention P LDS row stride (elems): 144B rows, 16B aligned

#if __has_builtin(__builtin_amdgcn_exp2f)
#define EXP2(x) __builtin_amdgcn_exp2f(x)
#else
#define EXP2(x) exp2f(x)
#endif

// direct global->LDS, 16B per lane; LDS dest = wave-uniform base + lane*16
__device__ __forceinline__ void g2l16(const bf16_t* g, bf16_t* l) {
  __builtin_amdgcn_global_load_lds((const AS1 u32*)g, (AS3 u32*)l, 16, 0, 0);
}

// pack two f32 -> packed bf16 pair (round-half-up; inputs finite >= 0 here)
__device__ __forceinline__ u32 pkbf(float a, float b) {
  u32 ua = __builtin_bit_cast(u32, a) + 0x8000u;
  u32 ub = __builtin_bit_cast(u32, b) + 0x8000u;
  return (ua >> 16) | (ub & 0xFFFF0000u);
}

// ---------------------------------------------------------------------------
// fp32 -> bf16 bulk convert for x, Wq, Wk, Wv, Wo (one dispatch, 1024 elems/blk)
// ---------------------------------------------------------------------------
__global__ __launch_bounds__(256) void cvt5(
    const float* __restrict__ s0, const float* __restrict__ s1,
    const float* __restrict__ s2, const float* __restrict__ s3,
    const float* __restrict__ s4,
    bf16_t* __restrict__ d0, bf16_t* __restrict__ d1, bf16_t* __restrict__ d2,
    bf16_t* __restrict__ d3, bf16_t* __restrict__ d4)
{
  int blk = blockIdx.x;
  const float* s; bf16_t* d; int off;
  if      (blk <  8192) { s = s0; d = d0; off = blk;         }  // x : 8388608
  else if (blk < 12288) { s = s1; d = d1; off = blk -  8192; }  // Wq: 4194304
  else if (blk < 13312) { s = s2; d = d2; off = blk - 12288; }  // Wk: 1048576
  else if (blk < 14336) { s = s3; d = d3; off = blk - 13312; }  // Wv: 1048576
  else                  { s = s4; d = d4; off = blk - 14336; }  // Wo: 4194304
  size_t i = (size_t)off * 1024 + threadIdx.x * 4;
  float4 v = *(const float4*)&s[i];
  bf16x4 t;
  t[0] = (bf16_t)v.x; t[1] = (bf16_t)v.y; t[2] = (bf16_t)v.z; t[3] = (bf16_t)v.w;
  *(bf16x4*)&d[i] = t;
}

// ---------------------------------------------------------------------------
// GEMM core v2 (PROVEN R8 pattern, kept for gemm_o): BK=32, double-buffered
// single-barrier pipelined K-loop, XOR-chunk swizzle. 32KB LDS.
// ---------------------------------------------------------------------------
__device__ __forceinline__ void gemm_core(
    const bf16_t* __restrict__ A, const bf16_t* __restrict__ B, int K,
    bf16_t* As0, bf16_t* As1, bf16_t* Bs0, bf16_t* Bs1, f32x4 (&acc)[4][4])
{
  const int tid = threadIdx.x, lane = tid & 63, w = tid >> 6;
  const int col = lane & 15, quad = lane >> 4;
  const int wm = w >> 1, wn = w & 1;
  const int lr = lane >> 2;
  const int lc = (((lane & 3) ^ ((lane >> 3) & 3)) << 3);  // swizzled stage chunk
  const int sw = ((quad ^ ((col >> 1) & 3)) << 3);         // swizzled read chunk
  const bf16_t* ga = A + (size_t)(w * 16 + lr) * K + lc;
  const bf16_t* gb = B + (size_t)(w * 16 + lr) * K + lc;
  const int lo0 = (w * 16) * 32, lo1 = (64 + w * 16) * 32;  // wave-uniform LDS bases

  // prologue: stage kb=0 into buffer 0
  g2l16(ga,                  As0 + lo0);
  g2l16(ga + (size_t)64 * K, As0 + lo1);
  g2l16(gb,                  Bs0 + lo0);
  g2l16(gb + (size_t)64 * K, Bs0 + lo1);

  const int nkb = K >> 5;
  for (int kb = 0; kb < nkb; ++kb) {
    __syncthreads();   // vmcnt(0): stage(kb) visible; prior reads of next buf done
    bf16_t* Ac = (kb & 1) ? As1 : As0;
    bf16_t* Bc = (kb & 1) ? Bs1 : Bs0;
    if (kb + 1 < nkb) {   // prefetch kb+1 into the other buffer
      bf16_t* An = (kb & 1) ? As0 : As1;
      bf16_t* Bn = (kb & 1) ? Bs0 : Bs1;
      const int k2 = (kb + 1) * 32;
      g2l16(ga + k2,                  An + lo0);
      g2l16(ga + k2 + (size_t)64 * K, An + lo1);
      g2l16(gb + k2,                  Bn + lo0);
      g2l16(gb + k2 + (size_t)64 * K, Bn + lo1);
    }

    bf16x8 af[4], bfr[4];
#pragma unroll
    for (int mt = 0; mt < 4; ++mt)
      af[mt] = *(const bf16x8*)&Ac[(wm * 64 + mt * 16 + col) * 32 + sw];
#pragma unroll
    for (int nt = 0; nt < 4; ++nt)
      bfr[nt] = *(const bf16x8*)&Bc[(wn * 64 + nt * 16 + col) * 32 + sw];
#pragma unroll
    for (int mt = 0; mt < 4; ++mt)
#pragma unroll
      for (int nt = 0; nt < 4; ++nt)
        acc[mt][nt] = __builtin_amdgcn_mfma_f32_16x16x32_bf16(af[mt], bfr[nt], acc[mt][nt], 0, 0, 0);
  }
}

// ---------------------------------------------------------------------------
// gemm_qkv8: 256x256 tile, 8 waves (2M x 4N), BK=64 split in two k-halves,
// 8-phase schedule with counted vmcnt gates (T3+T4) + setprio (T5).
//
// LDS = 8 half-tile regions of 16 KB: {A,B} x {slot E(even tile), O(odd)} x
// {k0,k1}.  Region layout [256 rows][32 k-elems], XOR-chunk swizzle (same
// math as gemm_core).  Iteration i processes tiles Te=2i (ph1-4), To=2i+1
// (ph5-8).  Phase reads:
//   ph1: A[E][k0] mh0 + B[E][k0](reload)   ph2: A[E][k0] mh1 (B held)
//   ph3: A[E][k1] mh0 + B[E][k1]           ph4: A[E][k1] mh1
//   ph5-8: same on slot O.
// Phase stages (region's old reads ended at previous closing barrier):
//   ph1: A[O][k1]<-To   ph2: B[O][k1]<-To   ph3: A[E][k0]<-Te+2
//   ph4: B[E][k0]<-Te+2 ph5: A[E][k1]<-Te+2 ph6: B[E][k1]<-Te+2
//   ph7: A[O][k0]<-To+2 ph8: B[O][k0]<-To+2
// Gates: vmcnt(4) at end of ph4 and ph8.  FIFO ledger: at each gate <=4
// outstanding = the 2 newest half-tiles (ph3,4 / ph7,8) => everything the
// next 4 phases read has landed.  Never drains to 0 except last iteration
// (no ph3/4 stages there to cover ph1/2, so i==15 gates vmcnt(0)).
// Prologue: tile0 all 4 halves + tile1 k0 halves (12 loads), vmcnt(4).
// ---------------------------------------------------------------------------
#define ARG(s,k) (LS + ((s)*2+(k))*8192)
#define BRG(s,k) (LS + 32768 + ((s)*2+(k))*8192)
#define STG(rg, gp) do { \
    g2l16((gp),                    (rg) + w*512); \
    g2l16((gp) + (size_t)128*2048, (rg) + 4096 + w*512); } while(0)
#define PH_LOADB(BR) \
  _Pragma("unroll") for (int nf = 0; nf < 4; ++nf) \
    bfr[nf] = *(const bf16x8*)&(BR)[(wn*64 + nf*16 + col)*32 + sw];
#define PH_LOADA(AR, MH) \
  _Pragma("unroll") for (int mf = 0; mf < 4; ++mf) \
    af[mf] = *(const bf16x8*)&(AR)[(wm*128 + (MH)*64 + mf*16 + col)*32 + sw];
#define PH_MID() \
  __builtin_amdgcn_s_barrier(); \
  asm volatile("s_waitcnt lgkmcnt(0)" ::: "memory"); \
  __builtin_amdgcn_sched_barrier(0); \
  __builtin_amdgcn_s_setprio(1)
#define PH_MFMA(MH) \
  _Pragma("unroll") for (int mf = 0; mf < 4; ++mf) \
  _Pragma("unroll") for (int nf = 0; nf < 4; ++nf) \
    acc[(MH)*4+mf][nf] = __builtin_amdgcn_mfma_f32_16x16x32_bf16(af[mf], bfr[nf], acc[(MH)*4+mf][nf], 0, 0, 0);
#define PH_END() \
  __builtin_amdgcn_s_setprio(0); \
  __builtin_amdgcn_s_barrier()

__global__ __launch_bounds__(512, 2) void gemm_qkv8(
    const bf16_t* __restrict__ xb, const bf16_t* __restrict__ Wqb,
    const bf16_t* __restrict__ Wkb, const bf16_t* __restrict__ Wvb,
    const float* __restrict__ cosT, const float* __restrict__ sinT,
    const float* __restrict__ wq, const float* __restrict__ wk,
    bf16_t* __restrict__ Qn, bf16_t* __restrict__ Kn, bf16_t* __restrict__ Vt)
{
  __shared__ bf16_t LS[65536];   // 128 KB: 8 gemm regions; reused for V-transpose
  const int tid = threadIdx.x, lane = tid & 63, w = tid >> 6;
  const int col = lane & 15, quad = lane >> 4;
  const int wm = w >> 2, wn = w & 3;          // 2M x 4N waves
  const int lr = lane >> 2;
  const int lc = (((lane & 3) ^ ((lane >> 3) & 3)) << 3);  // swizzled stage chunk
  const int sw = ((quad ^ ((col >> 1) & 3)) << 3);         // swizzled read chunk

  // XCD-chunked bijection: 192 blocks = 8 XCDs x (2 bm x 12 bn)
  const int xcd = blockIdx.x & 7, c = blockIdx.x >> 3;
  const int bm = xcd * 2 + c / 12, bn = c % 12;
  const bf16_t* Bp;
  if      (bn <  8) Bp = Wqb + (size_t)bn * 256 * 2048;
  else if (bn < 10) Bp = Wkb + (size_t)(bn - 8) * 256 * 2048;
  else              Bp = Wvb + (size_t)(bn - 10) * 256 * 2048;
  const bf16_t* Ap = xb + (size_t)bm * 256 * 2048;

  const bf16_t* ga = Ap + (size_t)(w * 16 + lr) * 2048 + lc;
  const bf16_t* gb = Bp + (size_t)(w * 16 + lr) * 2048 + lc;

  f32x4 acc[8][4] = {};
  bf16x8 af[4], bfr[4];

  // prologue: tile0 (4 halves) + tile1 k0 (2 halves)
  STG(ARG(0,0), ga);        STG(BRG(0,0), gb);
  STG(ARG(0,1), ga + 32);   STG(BRG(0,1), gb + 32);
  STG(ARG(1,0), ga + 64);   STG(BRG(1,0), gb + 64);
  asm volatile("s_waitcnt vmcnt(4)" ::: "memory");   // tile0 resident
  __builtin_amdgcn_s_barrier();

  for (int i = 0; i < 16; ++i) {
    const int To = 2 * i + 1;
    const int P2 = 2 * i + 2;          // Te+2; To+2 = P2+1
    const bool pe = (i < 15);
    // ---- ph1: E k0 mh0 (+B) ; stage A[O][k1] <- To ----
    PH_LOADB(BRG(0,0)); PH_LOADA(ARG(0,0), 0);
    STG(ARG(1,1), ga + To * 64 + 32);
    PH_MID(); PH_MFMA(0); PH_END();
    // ---- ph2: E k0 mh1 ; stage B[O][k1] <- To ----
    PH_LOADA(ARG(0,0), 1);
    STG(BRG(1,1), gb + To * 64 + 32);
    PH_MID(); PH_MFMA(1); PH_END();
    // ---- ph3: E k1 mh0 (+B) ; stage A[E][k0] <- Te+2 ----
    PH_LOADB(BRG(0,1)); PH_LOADA(ARG(0,1), 0);
    if (pe) STG(ARG(0,0), ga + P2 * 64);
    PH_MID(); PH_MFMA(0); PH_END();
    // ---- ph4: E k1 mh1 ; stage B[E][k0] <- Te+2 ; GATE ----
    PH_LOADA(ARG(0,1), 1);
    if (pe) STG(BRG(0,0), gb + P2 * 64);
    PH_MID(); PH_MFMA(1);
    __builtin_amdgcn_s_setprio(0);
    if (pe) { asm volatile("s_waitcnt vmcnt(4)" ::: "memory"); }
    else    { asm volatile("s_waitcnt vmcnt(0)" ::: "memory"); }
    __builtin_amdgcn_s_barrier();
    // ---- ph5: O k0 mh0 (+B) ; stage A[E][k1] <- Te+2 ----
    PH_LOADB(BRG(1,0)); PH_LOADA(ARG(1,0), 0);
    if (pe) STG(ARG(0,1), ga + P2 * 64 + 32);
    PH_MID(); PH_MFMA(0); PH_END();
    // ---- ph6: O k0 mh1 ; stage B[E][k1] <- Te+2 ----
    PH_LOADA(ARG(1,0), 1);
    if (pe) STG(BRG(0,1), gb + P2 * 64 + 32);
    PH_MID(); PH_MFMA(1); PH_END();
    // ---- ph7: O k1 mh0 (+B) ; stage A[O][k0] <- To+2 ----
    PH_LOADB(BRG(1,1)); PH_LOADA(ARG(1,1), 0);
    if (pe) STG(ARG(1,0), ga + (P2 + 1) * 64);
    PH_MID(); PH_MFMA(0); PH_END();
    // ---- ph8: O k1 mh1 ; stage B[O][k0] <- To+2 ; GATE ----
    PH_LOADA(ARG(1,1), 1);
    if (pe) STG(BRG(1,0), gb + (P2 + 1) * 64);
    PH_MID(); PH_MFMA(1);
    __builtin_amdgcn_s_setprio(0);
    asm volatile("s_waitcnt vmcnt(4)" ::: "memory");
    __builtin_amdgcn_s_barrier();
  }

  // ------------------------- epilogue -------------------------
  if (bn < 10) {  // Q or K: fused RMSNorm + RoPE; wave's 64-col span = 1 head
    const bool isQ = bn < 8;
    const float* wnv = isQ ? wq : wk;
    float w4[4];
#pragma unroll
    for (int nf = 0; nf < 4; ++nf) w4[nf] = wnv[nf * 16 + col];
    const int head = isQ ? bn * 4 + wn : (bn - 8) * 4 + wn;
    bf16_t* dst = (isQ ? Qn : Kn) + (size_t)head * 2048 * 64;
    const size_t bstride = isQ ? (size_t)32 * 2048 * 64 : (size_t)8 * 2048 * 64;
    const float qscale = 0.125f * 1.4426950408889634f;  // SCALE * log2(e)

#pragma unroll
    for (int mf = 0; mf < 8; ++mf)
#pragma unroll
      for (int r = 0; r < 4; ++r) {
        int row = bm * 256 + wm * 128 + mf * 16 + quad * 4 + r;
        int b = row >> 11, s = row & 2047;
        float v[4], ss = 0.f;
#pragma unroll
        for (int nf = 0; nf < 4; ++nf) { v[nf] = acc[mf][nf][r]; ss += v[nf] * v[nf]; }
        ss += __shfl_xor(ss, 1, 64);
        ss += __shfl_xor(ss, 2, 64);
        ss += __shfl_xor(ss, 4, 64);
        ss += __shfl_xor(ss, 8, 64);
        float rr = rsqrtf(ss * (1.0f / 64.0f) + 1e-6f);
        float t[4];
#pragma unroll
        for (int nf = 0; nf < 4; ++nf) t[nf] = v[nf] * rr * w4[nf];
        bf16_t* drow = dst + b * bstride + (size_t)s * 64;
#pragma unroll
        for (int nf = 0; nf < 4; ++nf) {
          int hd = nf * 16 + col;
          float rot = (nf < 2) ? -t[nf + 2] : t[nf - 2];
          float ov = t[nf] * cosT[s * 64 + hd] + rot * sinT[s * 64 + hd];
          if (isQ) ov *= qscale;
          drow[hd] = (bf16_t)ov;
        }
      }
  } else {
    // V: 2-pass LDS transpose (by wm group), write Vt[b][kvh][hd][s] directly.
    // s is PER-BATCH: b = bm>>3, s0g = (bm&7)*256 + hh*128.  (R4 bug: used
    // global token row here -> batch-1 V garbage + 4KB overflow into Qn.)
    const int b = bm >> 3;
    const int kvb = bn - 10;
#pragma unroll
    for (int hh = 0; hh < 2; ++hh) {
      asm volatile("s_waitcnt lgkmcnt(0)" ::: "memory");
      __builtin_amdgcn_s_barrier();        // LDS free (K-loop / prev pass done)
      if (wm == hh) {
#pragma unroll
        for (int mf = 0; mf < 8; ++mf)
#pragma unroll
          for (int nf = 0; nf < 4; ++nf)
#pragma unroll
            for (int r = 0; r < 4; ++r)
              LS[wn * 8704 + (nf * 16 + col) * 136 + mf * 16 + quad * 4 + r] =
                  (bf16_t)acc[mf][nf][r];
      }
      asm volatile("s_waitcnt lgkmcnt(0)" ::: "memory");
      __builtin_amdgcn_s_barrier();
      const int s0g = (bm & 7) * 256 + hh * 128;
      const int tile = tid >> 7, r128 = tid & 127;
      const int kvh = kvb * 4 + tile;
#pragma unroll
      for (int p = 0; p < 8; ++p) {
        int hd = p * 8 + (r128 >> 4);
        int sc = (r128 & 15) * 8;
        bf16x8 v = *(const bf16x8*)&LS[tile * 8704 + hd * 136 + sc];
        *(bf16x8*)&Vt[((size_t)((b * 8 + kvh) * 64) + hd) * 2048 + s0g + sc] = v;
      }
    }
  }
}

// output projection: A = Ao bf16 [4096,2048], B = Wob bf16, C = out fp32
// 1D grid 512, XCD-chunked swizzle (64/XCD = 4 bm x 16 bn).
__global__ __launch_bounds__(256, 4) void gemm_o(
    const bf16_t* __restrict__ Ao, const bf16_t* __restrict__ Wob,
    float* __restrict__ Cf)
{
  __shared__ bf16_t As[2][128 * 32], Bs[2][128 * 32];
  const int xcd = blockIdx.x & 7, c = blockIdx.x >> 3;
  const int bm = xcd * 4 + (c & 3), bn = c >> 2;
  f32x4 acc[4][4] = {};
  gemm_core(Ao + (size_t)bm * 128 * 2048, Wob + (size_t)bn * 128 * 2048, 2048,
            As[0], As[1], Bs[0], Bs[1], acc);

  const int lane = threadIdx.x & 63, w = threadIdx.x >> 6;
  const int col = lane & 15, quad = lane >> 4, wm = w >> 1, wn = w & 1;
#pragma unroll
  for (int mt = 0; mt < 4; ++mt)
#pragma unroll
    for (int r = 0; r < 4; ++r) {
      int row = bm * 128 + wm * 64 + mt * 16 + quad * 4 + r;
      float* crow = Cf + (size_t)row * 2048 + bn * 128 + wn * 64 + col;
#pragma unroll
      for (int nt = 0; nt < 4; ++nt)
        crow[nt * 16] = acc[mt][nt][r];
    }
}

// ---------------------------------------------------------------------------
// Flash attention v7 (unchanged — control): software-pipelined single-barrier
// K-loop, double-buffered K/V LDS, qt-descending LPT grid.
// ---------------------------------------------------------------------------
__global__ __launch_bounds__(256, 3) void attn(
    const bf16_t* __restrict__ Qn, const bf16_t* __restrict__ Kn,
    const bf16_t* __restrict__ Vt, bf16_t* __restrict__ Ao)
{
  __shared__ bf16_t KsL[2][64 * 32], KsH[2][64 * 32];   // K tile halves x2 buf
  __shared__ bf16_t VsL[2][64 * 32], VsH[2][64 * 32];   // V^T tile halves x2 buf
  __shared__ bf16_t Ps[128 * ASTR];                     // 4 waves x 32 rows

  const int tid = threadIdx.x, lane = tid & 63, w = tid >> 6;
  const int col = lane & 15, quad = lane >> 4;
  const int lr = lane >> 2;
  const int lcs = (((lane & 3) ^ ((lane >> 3) & 3)) << 3);  // swizzled stage chunk
  const int sw  = ((quad ^ ((col >> 1) & 3)) << 3);         // swizzled read chunk
  const int h = blockIdx.x, b = blockIdx.y;
  const int qt = 15 - blockIdx.z;         // qt slowest dim, descending (LPT)
  const int kvh = h >> 2;

  const bf16_t* Kb = Kn + ((size_t)(b * 8 + kvh)) * 2048 * 64;
  const bf16_t* Vb = Vt + ((size_t)(b * 8 + kvh)) * 64 * 2048;
  const bf16_t* Qb = Qn + (((size_t)(b * 32 + h)) * 2048 + qt * 128) * 64;
  const int lw = w * 512;                 // wave-uniform LDS sub-base

  // Q fragments in registers (B-operand layout), loaded once
  bf16x8 Qf[2][2];
#pragma unroll
  for (int mt = 0; mt < 2; ++mt)
#pragma unroll
    for (int kk = 0; kk < 2; ++kk)
      Qf[mt][kk] = *(const bf16x8*)&Qb[(w * 32 + mt * 16 + col) * 64 + kk * 32 + quad * 8];

  bf16x8 ones;
#pragma unroll
  for (int i = 0; i < 8; ++i) ones[i] = (bf16_t)1.0f;

  f32x4 o[2][4] = {};
  f32x4 lacc[2] = {};

  const int rowmin = qt * 128 + w * 32;
  const int rowmax = rowmin + 31;
  const int jmax = 2 * qt + 1;

  // prologue: stage tile 0 into buffer 0
  {
    const bf16_t* gk = &Kb[(size_t)(w * 16 + lr) * 64 + lcs];
    const bf16_t* gv = &Vb[(size_t)(w * 16 + lr) * 2048 + lcs];
    g2l16(gk,      &KsL[0][lw]);
    g2l16(gk + 32, &KsH[0][lw]);
    g2l16(gv,      &VsL[0][lw]);
    g2l16(gv + 32, &VsH[0][lw]);
  }

  for (int j = 0; j <= jmax; ++j) {
    __syncthreads();   // vmcnt(0): stage(j) visible; prior compute reads done
    if (j < jmax) {    // prefetch j+1 into the other buffer (block-uniform)
      const int nb = (j + 1) & 1;
      const bf16_t* gk = &Kb[(size_t)((j + 1) * 64 + w * 16 + lr) * 64 + lcs];
      const bf16_t* gv = &Vb[(size_t)(w * 16 + lr) * 2048 + (j + 1) * 64 + lcs];
      g2l16(gk,      &KsL[nb][lw]);
      g2l16(gk + 32, &KsH[nb][lw]);
      g2l16(gv,      &VsL[nb][lw]);
      g2l16(gv + 32, &VsH[nb][lw]);
    }

    if (j * 64 <= rowmax) {     // per-wave compute guard (fully-masked: skip)
      const int bf = j & 1;
      const bool needmask = (j * 64 + 63 > rowmin);

#pragma unroll
      for (int kt = 0; kt < 4; ++kt) {
        bf16x8 kf0 = *(const bf16x8*)&KsL[bf][(kt * 16 + col) * 32 + sw];
        bf16x8 kf1 = *(const bf16x8*)&KsH[bf][(kt * 16 + col) * 32 + sw];
        f32x4 st0 = {}, st1 = {};
        st0 = __builtin_amdgcn_mfma_f32_16x16x32_bf16(kf0, Qf[0][0], st0, 0, 0, 0);
        st0 = __builtin_amdgcn_mfma_f32_16x16x32_bf16(kf1, Qf[0][1], st0, 0, 0, 0);
        st1 = __builtin_amdgcn_mfma_f32_16x16x32_bf16(kf0, Qf[1][0], st1, 0, 0, 0);
        st1 = __builtin_amdgcn_mfma_f32_16x16x32_bf16(kf1, Qf[1][1], st1, 0, 0, 0);
        const int k0 = j * 64 + kt * 16 + quad * 4;
#pragma unroll
        for (int mt = 0; mt < 2; ++mt) {
          f32x4 st = mt ? st1 : st0;
          float p0 = EXP2(st[0]), p1 = EXP2(st[1]);
          float p2 = EXP2(st[2]), p3 = EXP2(st[3]);
          if (needmask) {   // wave-uniform branch (diagonal tiles only)
            const int qg = qt * 128 + w * 32 + mt * 16 + col;
            p0 = (k0 + 0 > qg) ? 0.f : p0;
            p1 = (k0 + 1 > qg) ? 0.f : p1;
            p2 = (k0 + 2 > qg) ? 0.f : p2;
            p3 = (k0 + 3 > qg) ? 0.f : p3;
          }
          uint2 pk = { pkbf(p0, p1), pkbf(p2, p3) };
          *(uint2*)&Ps[(w * 32 + mt * 16 + col) * ASTR + kt * 16 + quad * 4] = pk;
        }
      }
      // per-wave LDS scratch: drain writes before dependent reads
      asm volatile("s_waitcnt lgkmcnt(0)" ::: "memory");

#pragma unroll
      for (int kk = 0; kk < 2; ++kk) {
        const bf16_t* Vh = kk ? &VsH[bf][0] : &VsL[bf][0];
        bf16x8 pa0 = *(const bf16x8*)&Ps[(w * 32 + col) * ASTR + kk * 32 + quad * 8];
        bf16x8 pa1 = *(const bf16x8*)&Ps[(w * 32 + 16 + col) * ASTR + kk * 32 + quad * 8];
        lacc[0] = __builtin_amdgcn_mfma_f32_16x16x32_bf16(pa0, ones, lacc[0], 0, 0, 0);
        lacc[1] = __builtin_amdgcn_mfma_f32_16x16x32_bf16(pa1, ones, lacc[1], 0, 0, 0);
#pragma unroll
        for (int nt = 0; nt < 4; ++nt) {
          bf16x8 vf = *(const bf16x8*)&Vh[(nt * 16 + col) * 32 + sw];
          o[0][nt] = __builtin_amdgcn_mfma_f32_16x16x32_bf16(pa0, vf, o[0][nt], 0, 0, 0);
          o[1][nt] = __builtin_amdgcn_mfma_f32_16x16x32_bf16(pa1, vf, o[1][nt], 0, 0, 0);
        }
      }
    }
  }

  // epilogue: divide by l, write token-major bf16 [B*S, H*HD]
#pragma unroll
  for (int mt = 0; mt < 2; ++mt)
#pragma unroll
    for (int r = 0; r < 4; ++r) {
      float inv = 1.0f / lacc[mt][r];
      int row = b * 2048 + qt * 128 + w * 32 + mt * 16 + quad * 4 + r;
      bf16_t* orow = &Ao[(size_t)row * 2048 + h * 64 + col];
#pragma unroll
      for (int nt = 0; nt < 4; ++nt)
        orow[nt * 16] = (bf16_t)(o[mt][nt][r] * inv);
    }
}

// ---------------------------------------------------------------------------
extern "C" void kernel_launch(void* const* d_in, const int* in_sizes, int n_in,
                              void* d_out, int out_size, void* d_ws, size_t ws_size,
                              hipStream_t stream)
{
  const float* x    = (const float*)d_in[0];
  // d_in[1] = mask (unused; causal hardcoded)
  const float* cosT = (const float*)d_in[2];
  const float* sinT = (const float*)d_in[3];
  const float* Wq   = (const float*)d_in[4];
  const float* Wk   = (const float*)d_in[5];
  const float* Wv   = (const float*)d_in[6];
  const float* Wo   = (const float*)d_in[7];
  const float* wq   = (const float*)d_in[8];
  const float* wk   = (const float*)d_in[9];
  float* out = (float*)d_out;

  char* ws = (char*)d_ws;
  bf16_t* xb  = (bf16_t*)(ws);                 // 16777216  until gemm_qkv
  bf16_t* Ao  = (bf16_t*)(ws);                 // (reuses xb) attn -> gemm_o
  bf16_t* Wqb = (bf16_t*)(ws + 16777216);      //  8388608  until gemm_qkv
  bf16_t* Wkb = (bf16_t*)(ws + 25165824);      //  2097152
  bf16_t* Wvb = (bf16_t*)(ws + 27262976);      //  2097152
  bf16_t* Wob = (bf16_t*)(ws + 29360128);      //  8388608  until gemm_o
  bf16_t* Vt  = (bf16_t*)(ws + 37748736);      //  4194304  gemm_qkv -> attn
  bf16_t* Qn  = (bf16_t*)(ws + 41943040);      // 16777216  until attn
  bf16_t* Kn  = (bf16_t*)(ws + 58720256);      //  4194304  until attn
  // total 62914560 B

  cvt5<<<18432, 256, 0, stream>>>(x, Wq, Wk, Wv, Wo, xb, Wqb, Wkb, Wvb, Wob);
  gemm_qkv8<<<192, 512, 0, stream>>>(xb, Wqb, Wkb, Wvb, cosT, sinT, wq, wk, Qn, Kn, Vt);
  attn<<<dim3(32, 2, 16), 256, 0, stream>>>(Qn, Kn, Vt, Ao);
  gemm_o<<<512, 256, 0, stream>>>(Ao, Wob, out);
}

// Round 6
// 284.092 us; speedup vs baseline: 1.0442x; 1.0442x over previous
//
#include <hip/hip_runtime.h>

typedef __bf16 bf16_t;
typedef __bf16 bf16x8 __attribute__((ext_vector_type(8)));
typedef __bf16 bf16x4 __attribute__((ext_vector_type(4)));
typedef float f32x4 __attribute__((ext_vector_type(4)));
typedef unsigned int u32;

#define AS1 __attribute__((address_space(1)))
#define AS3 __attribute__((address_space(3)))

#define ASTR 72   // attention P LDS row stride (elems): 144B rows, 16B aligned

#if __has_builtin(__builtin_amdgcn_exp2f)
#define EXP2(x) __builtin_amdgcn_exp2f(x)
#else
#define EXP2(x) exp2f(x)
#endif

// direct global->LDS, 16B per lane; LDS dest = wave-uniform base + lane*16
__device__ __forceinline__ void g2l16(const bf16_t* g, bf16_t* l) {
  __builtin_amdgcn_global_load_lds((const AS1 u32*)g, (AS3 u32*)l, 16, 0, 0);
}

// pack two f32 -> packed bf16 pair (round-half-up; inputs finite >= 0 here)
__device__ __forceinline__ u32 pkbf(float a, float b) {
  u32 ua = __builtin_bit_cast(u32, a) + 0x8000u;
  u32 ub = __builtin_bit_cast(u32, b) + 0x8000u;
  return (ua >> 16) | (ub & 0xFFFF0000u);
}

// ---------------------------------------------------------------------------
// fp32 -> bf16 bulk convert for x, Wq, Wk, Wv, Wo (one dispatch, 1024 elems/blk)
// ---------------------------------------------------------------------------
__global__ __launch_bounds__(256) void cvt5(
    const float* __restrict__ s0, const float* __restrict__ s1,
    const float* __restrict__ s2, const float* __restrict__ s3,
    const float* __restrict__ s4,
    bf16_t* __restrict__ d0, bf16_t* __restrict__ d1, bf16_t* __restrict__ d2,
    bf16_t* __restrict__ d3, bf16_t* __restrict__ d4)
{
  int blk = blockIdx.x;
  const float* s; bf16_t* d; int off;
  if      (blk <  8192) { s = s0; d = d0; off = blk;         }  // x : 8388608
  else if (blk < 12288) { s = s1; d = d1; off = blk -  8192; }  // Wq: 4194304
  else if (blk < 13312) { s = s2; d = d2; off = blk - 12288; }  // Wk: 1048576
  else if (blk < 14336) { s = s3; d = d3; off = blk - 13312; }  // Wv: 1048576
  else                  { s = s4; d = d4; off = blk - 14336; }  // Wo: 4194304
  size_t i = (size_t)off * 1024 + threadIdx.x * 4;
  float4 v = *(const float4*)&s[i];
  bf16x4 t;
  t[0] = (bf16_t)v.x; t[1] = (bf16_t)v.y; t[2] = (bf16_t)v.z; t[3] = (bf16_t)v.w;
  *(bf16x4*)&d[i] = t;
}

// ---------------------------------------------------------------------------
// GEMM core v2 (PROVEN, for gemm_qkv at 3 blocks/CU): BK=32, double-buffered
// single-barrier pipelined K-loop, XOR-chunk swizzle. 32KB LDS.
// ---------------------------------------------------------------------------
__device__ __forceinline__ void gemm_core(
    const bf16_t* __restrict__ A, const bf16_t* __restrict__ B, int K,
    bf16_t* As0, bf16_t* As1, bf16_t* Bs0, bf16_t* Bs1, f32x4 (&acc)[4][4])
{
  const int tid = threadIdx.x, lane = tid & 63, w = tid >> 6;
  const int col = lane & 15, quad = lane >> 4;
  const int wm = w >> 1, wn = w & 1;
  const int lr = lane >> 2;
  const int lc = (((lane & 3) ^ ((lane >> 3) & 3)) << 3);  // swizzled stage chunk
  const int sw = ((quad ^ ((col >> 1) & 3)) << 3);         // swizzled read chunk
  const bf16_t* ga = A + (size_t)(w * 16 + lr) * K + lc;
  const bf16_t* gb = B + (size_t)(w * 16 + lr) * K + lc;
  const int lo0 = (w * 16) * 32, lo1 = (64 + w * 16) * 32;  // wave-uniform LDS bases

  // prologue: stage kb=0 into buffer 0
  g2l16(ga,                  As0 + lo0);
  g2l16(ga + (size_t)64 * K, As0 + lo1);
  g2l16(gb,                  Bs0 + lo0);
  g2l16(gb + (size_t)64 * K, Bs0 + lo1);

  const int nkb = K >> 5;
  for (int kb = 0; kb < nkb; ++kb) {
    __syncthreads();   // vmcnt(0): stage(kb) visible; prior reads of next buf done
    bf16_t* Ac = (kb & 1) ? As1 : As0;
    bf16_t* Bc = (kb & 1) ? Bs1 : Bs0;
    if (kb + 1 < nkb) {   // prefetch kb+1 into the other buffer
      bf16_t* An = (kb & 1) ? As0 : As1;
      bf16_t* Bn = (kb & 1) ? Bs0 : Bs1;
      const int k2 = (kb + 1) * 32;
      g2l16(ga + k2,                  An + lo0);
      g2l16(ga + k2 + (size_t)64 * K, An + lo1);
      g2l16(gb + k2,                  Bn + lo0);
      g2l16(gb + k2 + (size_t)64 * K, Bn + lo1);
    }

    bf16x8 af[4], bfr[4];
#pragma unroll
    for (int mt = 0; mt < 4; ++mt)
      af[mt] = *(const bf16x8*)&Ac[(wm * 64 + mt * 16 + col) * 32 + sw];
#pragma unroll
    for (int nt = 0; nt < 4; ++nt)
      bfr[nt] = *(const bf16x8*)&Bc[(wn * 64 + nt * 16 + col) * 32 + sw];
#pragma unroll
    for (int mt = 0; mt < 4; ++mt)
#pragma unroll
      for (int nt = 0; nt < 4; ++nt)
        acc[mt][nt] = __builtin_amdgcn_mfma_f32_16x16x32_bf16(af[mt], bfr[nt], acc[mt][nt], 0, 0, 0);
  }
}

// ---------------------------------------------------------------------------
// GEMM core v5 (for gemm_o, which is GRID-limited to 2 blocks/CU): BK=64,
// 64KB LDS double-buffer -> HALF the barrier drains of the BK=32 core, at
// zero occupancy cost (2 blocks x 64KB = 128KB <= 160KB).  m132's BK-up
// regression was the 3->2 occupancy drop; that penalty doesn't apply here.
// Row stride 64 elems = 128B = exact bank wrap, so chunk' = chunk ^ (row&7)
// XOR swizzle on BOTH stage-source and ds_read (2-way conflicts only).
// ---------------------------------------------------------------------------
__device__ __forceinline__ void gemm_core64(
    const bf16_t* __restrict__ A, const bf16_t* __restrict__ B, int K,
    bf16_t* As0, bf16_t* As1, bf16_t* Bs0, bf16_t* Bs1, f32x4 (&acc)[4][4])
{
  const int tid = threadIdx.x, lane = tid & 63, w = tid >> 6;
  const int col = lane & 15, quad = lane >> 4;
  const int wm = w >> 1, wn = w & 1;
  const int lr8 = lane >> 3;                     // row within 8-row wave span
  const int lc8 = (((lane & 7) ^ lr8) << 3);     // pre-swizzled source chunk
  const int rs = col & 7;                        // frag row & 7
  const bf16_t* ga = A + (size_t)(w * 8 + lr8) * K + lc8;
  const bf16_t* gb = B + (size_t)(w * 8 + lr8) * K + lc8;
  const int lo = (w * 8) * 64;                   // wave-uniform LDS base (elems)

  // stage one 128x64 operand tile: 4 wave-rounds of 32 rows each
#define STG64(dst, gp, koff) do { \
    g2l16((gp) + (koff),                   (dst) + lo);        \
    g2l16((gp) + (koff) + (size_t)32 * K,  (dst) + lo + 2048); \
    g2l16((gp) + (koff) + (size_t)64 * K,  (dst) + lo + 4096); \
    g2l16((gp) + (koff) + (size_t)96 * K,  (dst) + lo + 6144); \
  } while (0)

  STG64(As0, ga, 0);
  STG64(Bs0, gb, 0);

  const int nkb = K >> 6;   // 32 steps
  for (int kb = 0; kb < nkb; ++kb) {
    __syncthreads();   // vmcnt(0): stage(kb) visible; prior reads of next buf done
    bf16_t* Ac = (kb & 1) ? As1 : As0;
    bf16_t* Bc = (kb & 1) ? Bs1 : Bs0;
    if (kb + 1 < nkb) {
      bf16_t* An = (kb & 1) ? As0 : As1;
      bf16_t* Bn = (kb & 1) ? Bs0 : Bs1;
      STG64(An, ga, (kb + 1) * 64);
      STG64(Bn, gb, (kb + 1) * 64);
    }

#pragma unroll
    for (int kh = 0; kh < 2; ++kh) {
      const int sw64 = (((kh * 4 + quad) ^ rs) << 3);
      bf16x8 af[4], bfr[4];
#pragma unroll
      for (int mt = 0; mt < 4; ++mt)
        af[mt] = *(const bf16x8*)&Ac[(wm * 64 + mt * 16 + col) * 64 + sw64];
#pragma unroll
      for (int nt = 0; nt < 4; ++nt)
        bfr[nt] = *(const bf16x8*)&Bc[(wn * 64 + nt * 16 + col) * 64 + sw64];
#pragma unroll
      for (int mt = 0; mt < 4; ++mt)
#pragma unroll
        for (int nt = 0; nt < 4; ++nt)
          acc[mt][nt] = __builtin_amdgcn_mfma_f32_16x16x32_bf16(af[mt], bfr[nt], acc[mt][nt], 0, 0, 0);
    }
  }
#undef STG64
}

// ---------------------------------------------------------------------------
// merged QKV projection with FUSED RMSNorm + RoPE epilogue for Q and K,
// and FUSED V-transpose epilogue (writes Vt directly).  1D grid 768,
// XCD-chunked swizzle.  (R3-proven, byte-identical.)
// ---------------------------------------------------------------------------
__global__ __launch_bounds__(256, 4) void gemm_qkv(
    const bf16_t* __restrict__ xb, const bf16_t* __restrict__ Wqb,
    const bf16_t* __restrict__ Wkb, const bf16_t* __restrict__ Wvb,
    const float* __restrict__ cosT, const float* __restrict__ sinT,
    const float* __restrict__ wq, const float* __restrict__ wk,
    bf16_t* __restrict__ Qn, bf16_t* __restrict__ Kn, bf16_t* __restrict__ Vt)
{
  __shared__ bf16_t S[16384];   // 32 KB: gemm staging; reused as transpose tile
  // XCD-chunked bijection (768 blocks, 8 XCDs, 96/XCD = 4 bm x 24 bn)
  const int xcd = blockIdx.x & 7, c = blockIdx.x >> 3;
  const int bm = xcd * 4 + (c & 3), bn = c >> 2;
  const bf16_t* B;
  if      (bn < 16) B = Wqb + (size_t)bn * 128 * 2048;
  else if (bn < 20) B = Wkb + (size_t)(bn - 16) * 128 * 2048;
  else              B = Wvb + (size_t)(bn - 20) * 128 * 2048;

  f32x4 acc[4][4] = {};
  gemm_core(xb + (size_t)bm * 128 * 2048, B, 2048,
            &S[0], &S[4096], &S[8192], &S[12288], acc);

  const int lane = threadIdx.x & 63, w = threadIdx.x >> 6;
  const int col = lane & 15, quad = lane >> 4, wm = w >> 1, wn = w & 1;

  if (bn < 20) {  // Q or K: fused RMSNorm + RoPE, head-major output
    const bool isQ = bn < 16;
    const float* wnv = isQ ? wq : wk;
    float w4[4];
#pragma unroll
    for (int nt = 0; nt < 4; ++nt) w4[nt] = wnv[nt * 16 + col];
    bf16_t* dst = isQ ? Qn + ((size_t)(bn * 2 + wn)) * 2048 * 64
                      : Kn + ((size_t)((bn - 16) * 2 + wn)) * 2048 * 64;
    const size_t bstride = isQ ? (size_t)32 * 2048 * 64 : (size_t)8 * 2048 * 64;
    const float qscale = 0.125f * 1.4426950408889634f;  // SCALE * log2(e)

#pragma unroll
    for (int mt = 0; mt < 4; ++mt)
#pragma unroll
      for (int r = 0; r < 4; ++r) {
        int row = bm * 128 + wm * 64 + mt * 16 + quad * 4 + r;
        int b = row >> 11, s = row & 2047;
        float v[4], ss = 0.f;
#pragma unroll
        for (int nt = 0; nt < 4; ++nt) { v[nt] = acc[mt][nt][r]; ss += v[nt] * v[nt]; }
        ss += __shfl_xor(ss, 1, 64);
        ss += __shfl_xor(ss, 2, 64);
        ss += __shfl_xor(ss, 4, 64);
        ss += __shfl_xor(ss, 8, 64);
        float rr = rsqrtf(ss * (1.0f / 64.0f) + 1e-6f);
        float t[4];
#pragma unroll
        for (int nt = 0; nt < 4; ++nt) t[nt] = v[nt] * rr * w4[nt];
        bf16_t* drow = dst + b * bstride + (size_t)s * 64;
#pragma unroll
        for (int nt = 0; nt < 4; ++nt) {
          int hd = nt * 16 + col;
          float rot = (nt < 2) ? -t[nt + 2] : t[nt - 2];
          float ov = t[nt] * cosT[s * 64 + hd] + rot * sinT[s * 64 + hd];
          if (isQ) ov *= qscale;
          drow[hd] = (bf16_t)ov;
        }
      }
  } else {
    // V: transpose 128(tok) x 128(hd) block in LDS, write Vt[b][kvh][hd][s].
    const int vb = bn - 20;                   // 0..3 (hd-col block of 128)
    const int b = bm >> 4, s0 = (bm & 15) * 128;
    const int tid = threadIdx.x;
#pragma unroll
    for (int hh = 0; hh < 2; ++hh) {
      __syncthreads();                        // LDS free (core reads / prev pass)
      if (wn == hh) {
#pragma unroll
        for (int mt = 0; mt < 4; ++mt)
#pragma unroll
          for (int nt = 0; nt < 4; ++nt)
#pragma unroll
            for (int r = 0; r < 4; ++r)
              S[(nt * 16 + col) * 136 + wm * 64 + mt * 16 + quad * 4 + r] =
                  (bf16_t)acc[mt][nt][r];
      }
      __syncthreads();
      const int kvh = vb * 2 + hh;
#pragma unroll
      for (int p = 0; p < 4; ++p) {
        int hd = p * 16 + (tid >> 4);
        int sc = (tid & 15) * 8;
        bf16x8 v = *(const bf16x8*)&S[hd * 136 + sc];
        *(bf16x8*)&Vt[((size_t)((b * 8 + kvh) * 64) + hd) * 2048 + s0 + sc] = v;
      }
    }
  }
}

// output projection: A = Ao bf16 [4096,2048], B = Wob bf16, C = out fp32.
// 1D grid 512 (GRID-limited 2 blocks/CU) -> BK=64 core, 64KB LDS.
__global__ __launch_bounds__(256, 2) void gemm_o(
    const bf16_t* __restrict__ Ao, const bf16_t* __restrict__ Wob,
    float* __restrict__ Cf)
{
  __shared__ bf16_t As[2][128 * 64], Bs[2][128 * 64];   // 64 KB
  const int xcd = blockIdx.x & 7, c = blockIdx.x >> 3;
  const int bm = xcd * 4 + (c & 3), bn = c >> 2;
  f32x4 acc[4][4] = {};
  gemm_core64(Ao + (size_t)bm * 128 * 2048, Wob + (size_t)bn * 128 * 2048, 2048,
              As[0], As[1], Bs[0], Bs[1], acc);

  const int lane = threadIdx.x & 63, w = threadIdx.x >> 6;
  const int col = lane & 15, quad = lane >> 4, wm = w >> 1, wn = w & 1;
#pragma unroll
  for (int mt = 0; mt < 4; ++mt)
#pragma unroll
    for (int r = 0; r < 4; ++r) {
      int row = bm * 128 + wm * 64 + mt * 16 + quad * 4 + r;
      float* crow = Cf + (size_t)row * 2048 + bn * 128 + wn * 64 + col;
#pragma unroll
      for (int nt = 0; nt < 4; ++nt)
        crow[nt * 16] = acc[mt][nt][r];
    }
}

// ---------------------------------------------------------------------------
// Flash attention v7 (unchanged — control): software-pipelined single-barrier
// K-loop, double-buffered K/V LDS, qt-descending LPT grid.
// ---------------------------------------------------------------------------
__global__ __launch_bounds__(256, 3) void attn(
    const bf16_t* __restrict__ Qn, const bf16_t* __restrict__ Kn,
    const bf16_t* __restrict__ Vt, bf16_t* __restrict__ Ao)
{
  __shared__ bf16_t KsL[2][64 * 32], KsH[2][64 * 32];   // K tile halves x2 buf
  __shared__ bf16_t VsL[2][64 * 32], VsH[2][64 * 32];   // V^T tile halves x2 buf
  __shared__ bf16_t Ps[128 * ASTR];                     // 4 waves x 32 rows

  const int tid = threadIdx.x, lane = tid & 63, w = tid >> 6;
  const int col = lane & 15, quad = lane >> 4;
  const int lr = lane >> 2;
  const int lcs = (((lane & 3) ^ ((lane >> 3) & 3)) << 3);  // swizzled stage chunk
  const int sw  = ((quad ^ ((col >> 1) & 3)) << 3);         // swizzled read chunk
  const int h = blockIdx.x, b = blockIdx.y;
  const int qt = 15 - blockIdx.z;         // qt slowest dim, descending (LPT)
  const int kvh = h >> 2;

  const bf16_t* Kb = Kn + ((size_t)(b * 8 + kvh)) * 2048 * 64;
  const bf16_t* Vb = Vt + ((size_t)(b * 8 + kvh)) * 64 * 2048;
  const bf16_t* Qb = Qn + (((size_t)(b * 32 + h)) * 2048 + qt * 128) * 64;
  const int lw = w * 512;                 // wave-uniform LDS sub-base

  // Q fragments in registers (B-operand layout), loaded once
  bf16x8 Qf[2][2];
#pragma unroll
  for (int mt = 0; mt < 2; ++mt)
#pragma unroll
    for (int kk = 0; kk < 2; ++kk)
      Qf[mt][kk] = *(const bf16x8*)&Qb[(w * 32 + mt * 16 + col) * 64 + kk * 32 + quad * 8];

  bf16x8 ones;
#pragma unroll
  for (int i = 0; i < 8; ++i) ones[i] = (bf16_t)1.0f;

  f32x4 o[2][4] = {};
  f32x4 lacc[2] = {};

  const int rowmin = qt * 128 + w * 32;
  const int rowmax = rowmin + 31;
  const int jmax = 2 * qt + 1;

  // prologue: stage tile 0 into buffer 0
  {
    const bf16_t* gk = &Kb[(size_t)(w * 16 + lr) * 64 + lcs];
    const bf16_t* gv = &Vb[(size_t)(w * 16 + lr) * 2048 + lcs];
    g2l16(gk,      &KsL[0][lw]);
    g2l16(gk + 32, &KsH[0][lw]);
    g2l16(gv,      &VsL[0][lw]);
    g2l16(gv + 32, &VsH[0][lw]);
  }

  for (int j = 0; j <= jmax; ++j) {
    __syncthreads();   // vmcnt(0): stage(j) visible; prior compute reads done
    if (j < jmax) {    // prefetch j+1 into the other buffer (block-uniform)
      const int nb = (j + 1) & 1;
      const bf16_t* gk = &Kb[(size_t)((j + 1) * 64 + w * 16 + lr) * 64 + lcs];
      const bf16_t* gv = &Vb[(size_t)(w * 16 + lr) * 2048 + (j + 1) * 64 + lcs];
      g2l16(gk,      &KsL[nb][lw]);
      g2l16(gk + 32, &KsH[nb][lw]);
      g2l16(gv,      &VsL[nb][lw]);
      g2l16(gv + 32, &VsH[nb][lw]);
    }

    if (j * 64 <= rowmax) {     // per-wave compute guard (fully-masked: skip)
      const int bf = j & 1;
      const bool needmask = (j * 64 + 63 > rowmin);

#pragma unroll
      for (int kt = 0; kt < 4; ++kt) {
        bf16x8 kf0 = *(const bf16x8*)&KsL[bf][(kt * 16 + col) * 32 + sw];
        bf16x8 kf1 = *(const bf16x8*)&KsH[bf][(kt * 16 + col) * 32 + sw];
        f32x4 st0 = {}, st1 = {};
        st0 = __builtin_amdgcn_mfma_f32_16x16x32_bf16(kf0, Qf[0][0], st0, 0, 0, 0);
        st0 = __builtin_amdgcn_mfma_f32_16x16x32_bf16(kf1, Qf[0][1], st0, 0, 0, 0);
        st1 = __builtin_amdgcn_mfma_f32_16x16x32_bf16(kf0, Qf[1][0], st1, 0, 0, 0);
        st1 = __builtin_amdgcn_mfma_f32_16x16x32_bf16(kf1, Qf[1][1], st1, 0, 0, 0);
        const int k0 = j * 64 + kt * 16 + quad * 4;
#pragma unroll
        for (int mt = 0; mt < 2; ++mt) {
          f32x4 st = mt ? st1 : st0;
          float p0 = EXP2(st[0]), p1 = EXP2(st[1]);
          float p2 = EXP2(st[2]), p3 = EXP2(st[3]);
          if (needmask) {   // wave-uniform branch (diagonal tiles only)
            const int qg = qt * 128 + w * 32 + mt * 16 + col;
            p0 = (k0 + 0 > qg) ? 0.f : p0;
            p1 = (k0 + 1 > qg) ? 0.f : p1;
            p2 = (k0 + 2 > qg) ? 0.f : p2;
            p3 = (k0 + 3 > qg) ? 0.f : p3;
          }
          uint2 pk = { pkbf(p0, p1), pkbf(p2, p3) };
          *(uint2*)&Ps[(w * 32 + mt * 16 + col) * ASTR + kt * 16 + quad * 4] = pk;
        }
      }
      // per-wave LDS scratch: drain writes before dependent reads
      asm volatile("s_waitcnt lgkmcnt(0)" ::: "memory");

#pragma unroll
      for (int kk = 0; kk < 2; ++kk) {
        const bf16_t* Vh = kk ? &VsH[bf][0] : &VsL[bf][0];
        bf16x8 pa0 = *(const bf16x8*)&Ps[(w * 32 + col) * ASTR + kk * 32 + quad * 8];
        bf16x8 pa1 = *(const bf16x8*)&Ps[(w * 32 + 16 + col) * ASTR + kk * 32 + quad * 8];
        lacc[0] = __builtin_amdgcn_mfma_f32_16x16x32_bf16(pa0, ones, lacc[0], 0, 0, 0);
        lacc[1] = __builtin_amdgcn_mfma_f32_16x16x32_bf16(pa1, ones, lacc[1], 0, 0, 0);
#pragma unroll
        for (int nt = 0; nt < 4; ++nt) {
          bf16x8 vf = *(const bf16x8*)&Vh[(nt * 16 + col) * 32 + sw];
          o[0][nt] = __builtin_amdgcn_mfma_f32_16x16x32_bf16(pa0, vf, o[0][nt], 0, 0, 0);
          o[1][nt] = __builtin_amdgcn_mfma_f32_16x16x32_bf16(pa1, vf, o[1][nt], 0, 0, 0);
        }
      }
    }
  }

  // epilogue: divide by l, write token-major bf16 [B*S, H*HD]
#pragma unroll
  for (int mt = 0; mt < 2; ++mt)
#pragma unroll
    for (int r = 0; r < 4; ++r) {
      float inv = 1.0f / lacc[mt][r];
      int row = b * 2048 + qt * 128 + w * 32 + mt * 16 + quad * 4 + r;
      bf16_t* orow = &Ao[(size_t)row * 2048 + h * 64 + col];
#pragma unroll
      for (int nt = 0; nt < 4; ++nt)
        orow[nt * 16] = (bf16_t)(o[mt][nt][r] * inv);
    }
}

// ---------------------------------------------------------------------------
extern "C" void kernel_launch(void* const* d_in, const int* in_sizes, int n_in,
                              void* d_out, int out_size, void* d_ws, size_t ws_size,
                              hipStream_t stream)
{
  const float* x    = (const float*)d_in[0];
  // d_in[1] = mask (unused; causal hardcoded)
  const float* cosT = (const float*)d_in[2];
  const float* sinT = (const float*)d_in[3];
  const float* Wq   = (const float*)d_in[4];
  const float* Wk   = (const float*)d_in[5];
  const float* Wv   = (const float*)d_in[6];
  const float* Wo   = (const float*)d_in[7];
  const float* wq   = (const float*)d_in[8];
  const float* wk   = (const float*)d_in[9];
  float* out = (float*)d_out;

  char* ws = (char*)d_ws;
  bf16_t* xb  = (bf16_t*)(ws);                 // 16777216  until gemm_qkv
  bf16_t* Ao  = (bf16_t*)(ws);                 // (reuses xb) attn -> gemm_o
  bf16_t* Wqb = (bf16_t*)(ws + 16777216);      //  8388608  until gemm_qkv
  bf16_t* Wkb = (bf16_t*)(ws + 25165824);      //  2097152
  bf16_t* Wvb = (bf16_t*)(ws + 27262976);      //  2097152
  bf16_t* Wob = (bf16_t*)(ws + 29360128);      //  8388608  until gemm_o
  bf16_t* Vt  = (bf16_t*)(ws + 37748736);      //  4194304  gemm_qkv -> attn
  bf16_t* Qn  = (bf16_t*)(ws + 41943040);      // 16777216  until attn
  bf16_t* Kn  = (bf16_t*)(ws + 58720256);      //  4194304  until attn
  // total 62914560 B

  cvt5<<<18432, 256, 0, stream>>>(x, Wq, Wk, Wv, Wo, xb, Wqb, Wkb, Wvb, Wob);
  gemm_qkv<<<768, 256, 0, stream>>>(xb, Wqb, Wkb, Wvb, cosT, sinT, wq, wk, Qn, Kn, Vt);
  attn<<<dim3(32, 2, 16), 256, 0, stream>>>(Qn, Kn, Vt, Ao);
  gemm_o<<<512, 256, 0, stream>>>(Ao, Wob, out);
}